// Round 13
// baseline (267.748 us; speedup 1.0000x reference)
//
#include <hip/hip_runtime.h>
#include <cmath>
#include <stdint.h>

// ---------------------------------------------------------------------------
// AttentionLayer: att = softmax((q@W1+b1) @ (k@W2+b2)^T / sqrt(Sk)) @ v
// B=4, SQ=SK=2048, D=UNITS=1024, fp32 in/out, bf16 MFMA internally.
// R17 = R16 (best verified) with ONE change: the att GEMM moves from the
//      256-thr 128^2 engine (8 waves/CU, 604 TF) to the 512-thr 128^2
//      variant (R14's att512_phase, harness-verified inside the mega run):
//      512 blocks = 2/CU x 8 waves = 16 waves/CU -> doubled TLP against
//      the staging vmcnt drain, same tile/LDS/swizzle algebra.
// ---------------------------------------------------------------------------

typedef short short8 __attribute__((ext_vector_type(8)));
typedef float f32x4 __attribute__((ext_vector_type(4)));
typedef __bf16 bf16x8 __attribute__((ext_vector_type(8)));
typedef unsigned int u32x4 __attribute__((ext_vector_type(4)));

typedef __attribute__((address_space(3))) void lds_void;
typedef __attribute__((address_space(1))) void gbl_void;

__device__ __forceinline__ unsigned short f2b(float x) {
    unsigned u = __builtin_bit_cast(unsigned, x);
    u += 0x7fffu + ((u >> 16) & 1u);
    return (unsigned short)(u >> 16);
}

// ---------------------------------------------------------------------------
// Slim prep: z = 0..3 v-batch transpose (64x64 tiles), z=4 W1 transpose
// (+ rowsum zero stowaway), z=5 W2 transpose.  grid (64, 8, 6) x 256 thr.
// ---------------------------------------------------------------------------
__global__ void prep_kernel(const float* __restrict__ v,
                            const float* __restrict__ W1,
                            const float* __restrict__ W2,
                            unsigned short* __restrict__ vT,
                            unsigned short* __restrict__ W1t,
                            unsigned short* __restrict__ W2t,
                            float* __restrict__ rs) {
    const int bz = blockIdx.z;
    const int t = threadIdx.x;
    const int tid2 = blockIdx.y * 64 + blockIdx.x;   // 0..511

    // ---- rowsum-zero stowaway: 32 blocks of the z=4 slice ----
    if (bz == 4 && tid2 >= 256 && tid2 < 288) {
        if (rs) rs[(tid2 - 256) * 256 + t] = 0.f;
        return;
    }

    __shared__ float tile[64][65];
    const float* in;
    unsigned short* out;
    int R, C;
    if (bz < 4) {
        R = 2048; C = 1024;                 // v: 32 row-tiles x 16 col-tiles
        in = v + (long)bz * R * C;
        out = vT + (long)bz * R * C;
    } else {
        R = 1024; C = 1024;                 // W: 16 x 16 tiles
        if (tid2 >= 256) return;
        in = (bz == 4) ? W1 : W2;
        out = (bz == 4) ? W1t : W2t;
    }
    const int rt = (tid2 >> 4) * 64;
    const int ct = (tid2 & 15) * 64;

    {
        const int rr = t >> 2;              // 0..63
        const int cb = (t & 3) * 16;        // 0,16,32,48
        const float* src = in + (long)(rt + rr) * C + ct + cb;
#pragma unroll
        for (int u = 0; u < 4; u++) {
            float4 a = *(const float4*)(src + 4 * u);
            tile[rr][cb + 4 * u + 0] = a.x;
            tile[rr][cb + 4 * u + 1] = a.y;
            tile[rr][cb + 4 * u + 2] = a.z;
            tile[rr][cb + 4 * u + 3] = a.w;
        }
    }
    __syncthreads();
    {
        const int cc = t >> 2;              // 0..63
        const int rb = (t & 3) * 16;        // 0,16,32,48
        unsigned short* dst = out + (long)(ct + cc) * R + rt + rb;
#pragma unroll
        for (int u = 0; u < 2; u++) {
            union { short8 v8; unsigned short us[8]; } o;
#pragma unroll
            for (int e = 0; e < 8; e++) o.us[e] = f2b(tile[rb + 8 * u + e][cc]);
            *(short8*)(dst + 8 * u) = o.v8;
        }
    }
}

__device__ __forceinline__ void load16_to_lds(const unsigned short* g,
                                              unsigned short* l) {
    __builtin_amdgcn_global_load_lds((gbl_void*)g, (lds_void*)l, 16, 0, 0);
}

// ---------------------------------------------------------------------------
// 256x128 bf16 GEMM: C[M][N] = A[M][K] * Bt[N][K]^T, BK=64 (48 KB LDS),
// 512 thr = 8 waves (4Mx2N), each wave 4x4 of 16x16x32 MFMA per sub-k.
// LDS XOR swizzle (phys chunk = logical ^ (row&7)); XCD-stripe block remap.
// Single-buffered 2-barrier loop; latency hidden by 2 blocks/CU residency.
// CASTA=1: A is fp32 (Afq for bz=0, Afk for bz=1), reg-staged with
//          v_cvt_pk_bf16_f32 (RTNE == f2b) + ds_write_b128.
// MODE 0: bf16 out, + bias (bias1 used when bz==1 -- merged l1/l2)
// MODE 1: bf16 out = exp(acc*scale), atomicAdd per-row sums into rowsum
// ---------------------------------------------------------------------------
template <int MODE, int CASTA>
__global__ __launch_bounds__(512, 4) void gemm256_kernel(
                               const unsigned short* __restrict__ A,
                               const unsigned short* __restrict__ Bt,
                               const float* __restrict__ bias0,
                               const float* __restrict__ bias1,
                               float* __restrict__ rowsum,
                               void* __restrict__ Cout,
                               int M, int N, int K,
                               float scale,
                               long sA, long sB, long sC,
                               const float* __restrict__ Afq,
                               const float* __restrict__ Afk) {
    __shared__ __align__(16) unsigned short As[256 * 64];  // 32 KB
    __shared__ __align__(16) unsigned short Bs[128 * 64];  // 16 KB

    // ---- XCD-aware tile remap (bijective) ----
    int bx, by, bz;
    {
        const int nx = gridDim.x;
        const int Rt = gridDim.y * gridDim.z;
        if ((Rt & 7) == 0) {
            int flat = ((int)blockIdx.z * gridDim.y + blockIdx.y) * nx + blockIdx.x;
            int rpx = Rt >> 3;
            int c = flat & 7;
            int j = flat >> 3;
            bx = j / rpx;
            int yg = c * rpx + (j - bx * rpx);
            bz = yg / gridDim.y;
            by = yg - bz * gridDim.y;
        } else {
            bx = blockIdx.x; by = blockIdx.y; bz = blockIdx.z;
        }
    }

    Bt += (long)bz * sB;

    const int t = threadIdx.x;
    const int lane = t & 63;
    const int wave = t >> 6;               // 0..7
    const int wm = wave >> 1, wn = wave & 1;  // 4M x 2N
    const int row0 = by * 256;
    const int col0 = bx * 128;

    // staging: lane l -> row group l>>3 (8 rows/issue), phys chunk l&7;
    // source chunk XOR'd so phys = logical ^ (row&7)
    const int rS = lane >> 3;
    const int kOffS = ((lane & 7) ^ rS) * 8;
    const unsigned short* gA[4];
    const float* fA[4];
    unsigned short* lA[4];
    const unsigned short* gB[2];
    unsigned short* lB[2];
#pragma unroll
    for (int i = 0; i < 4; i++) {
        const int rowl = wave * 32 + i * 8;
        lA[i] = As + rowl * 64;
        if (CASTA) {
            const float* Af = bz ? Afk : Afq;
            fA[i] = Af + (long)(row0 + rowl + rS) * K + kOffS;
        } else {
            gA[i] = A + (long)bz * sA + (long)(row0 + rowl + rS) * K + kOffS;
        }
    }
#pragma unroll
    for (int i = 0; i < 2; i++) {
        const int rowl = wave * 16 + i * 8;
        gB[i] = Bt + (long)(col0 + rowl + rS) * K + kOffS;
        lB[i] = Bs + rowl * 64;
    }

    const int lr = lane & 15;
    const int quad = lane >> 4;
    const int pc0 = (quad ^ (lr & 7)) * 8;
    const int pc1 = ((4 + quad) ^ (lr & 7)) * 8;

    f32x4 acc[4][4];
#pragma unroll
    for (int i = 0; i < 4; i++)
#pragma unroll
        for (int j = 0; j < 4; j++) acc[i][j] = f32x4{0.f, 0.f, 0.f, 0.f};

    for (int k0 = 0; k0 < K; k0 += 64) {
#pragma unroll
        for (int i = 0; i < 2; i++) load16_to_lds(gB[i] + k0, lB[i]);
        if (CASTA) {
            // reg-stage A: fp32 -> bf16 (RTNE cvt_pk) -> LDS, same layout
            // as the gload_lds path (base + lane*16B).
#pragma unroll
            for (int i = 0; i < 4; i++) {
                const float* s = fA[i] + k0;
                float4 x = *(const float4*)(s);
                float4 y = *(const float4*)(s + 4);
                unsigned w0, w1, w2, w3;
                asm("v_cvt_pk_bf16_f32 %0, %1, %2" : "=v"(w0) : "v"(x.x), "v"(x.y));
                asm("v_cvt_pk_bf16_f32 %0, %1, %2" : "=v"(w1) : "v"(x.z), "v"(x.w));
                asm("v_cvt_pk_bf16_f32 %0, %1, %2" : "=v"(w2) : "v"(y.x), "v"(y.y));
                asm("v_cvt_pk_bf16_f32 %0, %1, %2" : "=v"(w3) : "v"(y.z), "v"(y.w));
                *(u32x4*)(lA[i] + lane * 8) = u32x4{w0, w1, w2, w3};
            }
        } else {
#pragma unroll
            for (int i = 0; i < 4; i++) load16_to_lds(gA[i] + k0, lA[i]);
        }
        __syncthreads();

#pragma unroll
        for (int ks = 0; ks < 2; ks++) {
            const int pc = ks ? pc1 : pc0;
            bf16x8 a[4], b[4];
#pragma unroll
            for (int i = 0; i < 4; i++) {
                a[i] = __builtin_bit_cast(bf16x8,
                    *(const short8*)(As + (wm * 64 + i * 16 + lr) * 64 + pc));
                b[i] = __builtin_bit_cast(bf16x8,
                    *(const short8*)(Bs + (wn * 64 + i * 16 + lr) * 64 + pc));
            }
#pragma unroll
            for (int i = 0; i < 4; i++)
#pragma unroll
                for (int j = 0; j < 4; j++)
                    acc[i][j] = __builtin_amdgcn_mfma_f32_16x16x32_bf16(
                        a[i], b[j], acc[i][j], 0, 0, 0);
        }
        __syncthreads();
    }

    // ---- epilogue (C/D layout: col = lane&15, row = quad*4 + reg) ----
    const long cbase = (long)bz * sC;

    if (MODE == 0) {
        const float* bp = (bz && bias1) ? bias1 : bias0;
#pragma unroll
        for (int j = 0; j < 4; j++) {
            const int gcol = col0 + wn * 64 + j * 16 + lr;
            const float bv = bp[gcol];
#pragma unroll
            for (int i = 0; i < 4; i++) {
                const int growb = row0 + wm * 64 + i * 16 + quad * 4;
#pragma unroll
                for (int r = 0; r < 4; r++) {
                    float val = acc[i][j][r] * scale + bv;
                    ((unsigned short*)Cout)[cbase + (long)(growb + r) * N + gcol] = f2b(val);
                }
            }
        }
    } else {  // MODE == 1
        float psum[4][4];
#pragma unroll
        for (int i = 0; i < 4; i++)
#pragma unroll
            for (int r = 0; r < 4; r++) psum[i][r] = 0.f;
#pragma unroll
        for (int j = 0; j < 4; j++) {
            const int gcol = col0 + wn * 64 + j * 16 + lr;
#pragma unroll
            for (int i = 0; i < 4; i++) {
                const int growb = row0 + wm * 64 + i * 16 + quad * 4;
#pragma unroll
                for (int r = 0; r < 4; r++) {
                    float e = __expf(acc[i][j][r] * scale);
                    psum[i][r] += e;
                    ((unsigned short*)Cout)[cbase + (long)(growb + r) * N + gcol] = f2b(e);
                }
            }
        }
        // reduce across the 16 lr lanes (xor masks 1,2,4,8 keep quad bits)
#pragma unroll
        for (int i = 0; i < 4; i++)
#pragma unroll
            for (int r = 0; r < 4; r++) {
                float s = psum[i][r];
                s += __shfl_xor(s, 1);
                s += __shfl_xor(s, 2);
                s += __shfl_xor(s, 4);
                s += __shfl_xor(s, 8);
                if (lr == 0) {
                    const int grow = row0 + wm * 64 + i * 16 + quad * 4 + r;
                    atomicAdd(rowsum + (long)bz * M + grow, s);
                }
            }
    }
}

// ---------------------------------------------------------------------------
// att: 128x128 tile @ 512 thr (8 waves 4Mx2N, per-wave 32x64, acc[2][4]).
// Same staging/swizzle algebra as the other engines; indexing harness-
// verified in R14's mega run. 512 blocks = 2/CU -> 16 waves/CU TLP.
// out = (sc @ vT^T) / rowsum[row], fp32.
// ---------------------------------------------------------------------------
__global__ __launch_bounds__(512, 4) void att512_kernel(
        const unsigned short* __restrict__ A,   // sc [B][2048][2048] bf16
        const unsigned short* __restrict__ Bt,  // vT [B][1024][2048] bf16
        const float* __restrict__ rowsum,
        float* __restrict__ out) {
    __shared__ __align__(16) unsigned short As[128 * 64];  // 16 KB
    __shared__ __align__(16) unsigned short Bs[128 * 64];  // 16 KB

    // ---- XCD-aware tile remap (bijective; Rt = 16*4 = 64, %8==0) ----
    int bx, by, bz;
    {
        const int nx = gridDim.x;
        const int Rt = gridDim.y * gridDim.z;
        int flat = ((int)blockIdx.z * gridDim.y + blockIdx.y) * nx + blockIdx.x;
        int rpx = Rt >> 3;
        int c = flat & 7;
        int j = flat >> 3;
        bx = j / rpx;
        int yg = c * rpx + (j - bx * rpx);
        bz = yg / gridDim.y;
        by = yg - bz * gridDim.y;
    }

    const int M = 2048, N = 1024, K = 2048;
    const long sA = (long)M * K, sB = (long)N * K, sC = (long)M * N;
    const unsigned short* Ab  = A  + (long)bz * sA;
    const unsigned short* Btb = Bt + (long)bz * sB;

    const int t = threadIdx.x;
    const int lane = t & 63;
    const int w = t >> 6;
    const int wm = w >> 1, wn = w & 1;     // 4M x 2N
    const int row0 = by * 128;
    const int col0 = bx * 128;

    const int rS = lane >> 3;
    const int kOffS = ((lane & 7) ^ rS) * 8;
    const unsigned short* gA[2];
    unsigned short* lA[2];
    const unsigned short* gB[2];
    unsigned short* lB[2];
#pragma unroll
    for (int i = 0; i < 2; i++) {
        const int rowl = w * 16 + i * 8;
        gA[i] = Ab  + (long)(row0 + rowl + rS) * K + kOffS;
        lA[i] = As + rowl * 64;
        gB[i] = Btb + (long)(col0 + rowl + rS) * K + kOffS;
        lB[i] = Bs + rowl * 64;
    }

    const int lr = lane & 15;
    const int quad = lane >> 4;
    const int pc0 = (quad ^ (lr & 7)) * 8;
    const int pc1 = ((4 + quad) ^ (lr & 7)) * 8;

    f32x4 acc[2][4];
#pragma unroll
    for (int i = 0; i < 2; i++)
#pragma unroll
        for (int j = 0; j < 4; j++) acc[i][j] = f32x4{0.f, 0.f, 0.f, 0.f};

    for (int k0 = 0; k0 < K; k0 += 64) {
#pragma unroll
        for (int i = 0; i < 2; i++) {
            load16_to_lds(gA[i] + k0, lA[i]);
            load16_to_lds(gB[i] + k0, lB[i]);
        }
        __syncthreads();
#pragma unroll
        for (int ks = 0; ks < 2; ks++) {
            const int pc = ks ? pc1 : pc0;
            bf16x8 a[2], b[4];
#pragma unroll
            for (int i = 0; i < 2; i++)
                a[i] = __builtin_bit_cast(bf16x8,
                    *(const short8*)(As + (wm * 32 + i * 16 + lr) * 64 + pc));
#pragma unroll
            for (int j = 0; j < 4; j++)
                b[j] = __builtin_bit_cast(bf16x8,
                    *(const short8*)(Bs + (wn * 64 + j * 16 + lr) * 64 + pc));
#pragma unroll
            for (int i = 0; i < 2; i++)
#pragma unroll
                for (int j = 0; j < 4; j++)
                    acc[i][j] = __builtin_amdgcn_mfma_f32_16x16x32_bf16(
                        a[i], b[j], acc[i][j], 0, 0, 0);
        }
        __syncthreads();
    }

    const long cbase = (long)bz * sC;
#pragma unroll
    for (int i = 0; i < 2; i++) {
        const int growb = row0 + wm * 32 + i * 16 + quad * 4;
#pragma unroll
        for (int r = 0; r < 4; r++) {
            const float inv = 1.0f / rowsum[(long)bz * M + growb + r];
#pragma unroll
            for (int j = 0; j < 4; j++) {
                const int gcol = col0 + wn * 64 + j * 16 + lr;
                out[cbase + (long)(growb + r) * N + gcol] = acc[i][j][r] * inv;
            }
        }
    }
}

// ---------------------------------------------------------------------------
extern "C" void kernel_launch(void* const* d_in, const int* in_sizes, int n_in,
                              void* d_out, int out_size, void* d_ws, size_t ws_size,
                              hipStream_t stream) {
    const float* q   = (const float*)d_in[0];
    const float* k   = (const float*)d_in[1];
    const float* v   = (const float*)d_in[2];
    const float* W1w = (const float*)d_in[3];
    const float* W1b = (const float*)d_in[4];
    const float* W2w = (const float*)d_in[5];
    const float* W2b = (const float*)d_in[6];
    float* out = (float*)d_out;

    const int B = 4, SQ = 2048, SK = 2048, D = 1024, U = 1024;
    char* ws = (char*)d_ws;
    const size_t MB = 1024 * 1024;
    unsigned short* vT  = (unsigned short*)(ws + 32 * MB);  // 16 MB [B][D][SK]
    unsigned short* W1t = (unsigned short*)(ws + 48 * MB);  // 2 MB  [U][D]
    unsigned short* W2t = (unsigned short*)(ws + 50 * MB);  // 2 MB
    unsigned short* l1  = (unsigned short*)(ws + 52 * MB);  // 16 MB [B*SQ][U]
    unsigned short* l2  = (unsigned short*)(ws + 68 * MB);  // 16 MB
    unsigned short* sc  = (unsigned short*)(ws + 0);        // 32 MB [B][SQ][SK]

    // rowsum: fresh slot at 84 MB, zeroed inside prep (no memset dispatch);
    // fallback: W2t slot + memset between l1l2 and score.
    float* rowsum;
    bool prep_zeroes_rowsum;
    if (ws_size >= 85 * MB) {
        rowsum = (float*)(ws + 84 * MB);
        prep_zeroes_rowsum = true;
    } else {
        rowsum = (float*)(ws + 50 * MB);
        prep_zeroes_rowsum = false;
    }

    // 1: prep (v/W transposes + rowsum zero) -- q/k casts in-GEMM
    prep_kernel<<<dim3(64, 8, 6), 256, 0, stream>>>(
        v, W1w, W2w, vT, W1t, W2t,
        prep_zeroes_rowsum ? rowsum : nullptr);
    // 2: merged l1 = q@W1+b1 (bz=0), l2 = k@W2+b2 (bz=1); A cast in-flight
    gemm256_kernel<0, 1><<<dim3(U / 128, (B * SQ) / 256, 2), 512, 0, stream>>>(
        nullptr, W1t, W1b, W2b, nullptr, l1, B * SQ, U, D, 1.0f,
        0, (long)1024 * 1024, (long)8 * 1024 * 1024, q, k);
    // 3 (fallback only): zero rowsum in the W2t slot after l1l2 read it
    if (!prep_zeroes_rowsum)
        hipMemsetAsync(rowsum, 0, (size_t)B * SQ * sizeof(float), stream);
    // 4: sc = exp(l1 @ l2^T / sqrt(SK)) bf16 + rowsum atomics
    const float invs = 1.0f / sqrtf((float)SK);
    gemm256_kernel<1, 0><<<dim3(SK / 128, SQ / 256, B), 512, 0, stream>>>(
        l1, l2, nullptr, nullptr, rowsum, sc, SQ, SK, U, invs,
        (long)SQ * U, (long)SK * U, (long)SQ * SK, nullptr, nullptr);
    // 5: att = (sc @ vT^T) / rowsum[row]  (fp32 out) -- 512-thr 128^2,
    //    512 blocks = 2/CU (16 waves/CU)
    att512_kernel<<<dim3(D / 128, SQ / 128, B), 512, 0, stream>>>(
        sc, vT, rowsum, out);
}

// Round 14
// 262.808 us; speedup vs baseline: 1.0188x; 1.0188x over previous
//
#include <hip/hip_runtime.h>
#include <cmath>
#include <stdint.h>

// ---------------------------------------------------------------------------
// AttentionLayer: att = softmax((q@W1+b1) @ (k@W2+b2)^T / sqrt(Sk)) @ v
// B=4, SQ=SK=2048, D=UNITS=1024, fp32 in/out, bf16 MFMA internally.
// R18 = R17 with l1l2 rebuilt as l1l2f: A staged as FP32 via
//      global_load_lds (async, un-serializable by the compiler), cast
//      fp32->bf16 moved to the fragment-read side (ds_read_b128 x2 +
//      v_cvt_pk x4 per fragment). LDS = 64KB fp32 A + 16KB bf16 B = 80KB
//      exactly -> still 2 blocks/CU. Swizzle: staged phys chunk =
//      logical ^ (row&15) via pre-swizzled global source; read phys =
//      chunk ^ lr (2 lanes/bank = free). score/att/prep frozen from R17.
// ---------------------------------------------------------------------------

typedef short short8 __attribute__((ext_vector_type(8)));
typedef float f32x4 __attribute__((ext_vector_type(4)));
typedef __bf16 bf16x8 __attribute__((ext_vector_type(8)));
typedef unsigned int u32x4 __attribute__((ext_vector_type(4)));

typedef __attribute__((address_space(3))) void lds_void;
typedef __attribute__((address_space(1))) void gbl_void;

__device__ __forceinline__ unsigned short f2b(float x) {
    unsigned u = __builtin_bit_cast(unsigned, x);
    u += 0x7fffu + ((u >> 16) & 1u);
    return (unsigned short)(u >> 16);
}

// ---------------------------------------------------------------------------
// Slim prep: z = 0..3 v-batch transpose (64x64 tiles), z=4 W1 transpose
// (+ rowsum zero stowaway), z=5 W2 transpose.  grid (64, 8, 6) x 256 thr.
// ---------------------------------------------------------------------------
__global__ void prep_kernel(const float* __restrict__ v,
                            const float* __restrict__ W1,
                            const float* __restrict__ W2,
                            unsigned short* __restrict__ vT,
                            unsigned short* __restrict__ W1t,
                            unsigned short* __restrict__ W2t,
                            float* __restrict__ rs) {
    const int bz = blockIdx.z;
    const int t = threadIdx.x;
    const int tid2 = blockIdx.y * 64 + blockIdx.x;   // 0..511

    // ---- rowsum-zero stowaway: 32 blocks of the z=4 slice ----
    if (bz == 4 && tid2 >= 256 && tid2 < 288) {
        if (rs) rs[(tid2 - 256) * 256 + t] = 0.f;
        return;
    }

    __shared__ float tile[64][65];
    const float* in;
    unsigned short* out;
    int R, C;
    if (bz < 4) {
        R = 2048; C = 1024;                 // v: 32 row-tiles x 16 col-tiles
        in = v + (long)bz * R * C;
        out = vT + (long)bz * R * C;
    } else {
        R = 1024; C = 1024;                 // W: 16 x 16 tiles
        if (tid2 >= 256) return;
        in = (bz == 4) ? W1 : W2;
        out = (bz == 4) ? W1t : W2t;
    }
    const int rt = (tid2 >> 4) * 64;
    const int ct = (tid2 & 15) * 64;

    {
        const int rr = t >> 2;              // 0..63
        const int cb = (t & 3) * 16;        // 0,16,32,48
        const float* src = in + (long)(rt + rr) * C + ct + cb;
#pragma unroll
        for (int u = 0; u < 4; u++) {
            float4 a = *(const float4*)(src + 4 * u);
            tile[rr][cb + 4 * u + 0] = a.x;
            tile[rr][cb + 4 * u + 1] = a.y;
            tile[rr][cb + 4 * u + 2] = a.z;
            tile[rr][cb + 4 * u + 3] = a.w;
        }
    }
    __syncthreads();
    {
        const int cc = t >> 2;              // 0..63
        const int rb = (t & 3) * 16;        // 0,16,32,48
        unsigned short* dst = out + (long)(ct + cc) * R + rt + rb;
#pragma unroll
        for (int u = 0; u < 2; u++) {
            union { short8 v8; unsigned short us[8]; } o;
#pragma unroll
            for (int e = 0; e < 8; e++) o.us[e] = f2b(tile[rb + 8 * u + e][cc]);
            *(short8*)(dst + 8 * u) = o.v8;
        }
    }
}

__device__ __forceinline__ void load16_to_lds(const unsigned short* g,
                                              unsigned short* l) {
    __builtin_amdgcn_global_load_lds((gbl_void*)g, (lds_void*)l, 16, 0, 0);
}

// ---------------------------------------------------------------------------
// l1l2f: C[8192][1024] = A[8192][1024](fp32) * Wt[1024][1024]^T + bias,
// bf16 out. 256x128 tile, BK=64, 512 thr = 8 waves (4Mx2N).
// A staged as FP32 via global_load_lds: per wave 8 issues/K-step, issue i
// covers rows wave*32+i*4+(lane>>4), phys 16B-chunk = lane&15, global
// logical chunk = (lane&15) ^ ((i*4 + (lane>>4)) & 15)  [= phys ^ (row&15)].
// Fragment read: row r (r&15 == lr), logical chunks c0=ks*8+quad*2, c0+1;
// phys = chunk ^ lr -> 16 distinct chunks per 16-lane group (2/bank, free).
// fp32 -> bf16 via v_cvt_pk_bf16_f32 (RTNE == f2b) before MFMA.
// B path identical to the proven bf16 engine.
// ---------------------------------------------------------------------------
__global__ __launch_bounds__(512, 4) void l1l2f_kernel(
        const float* __restrict__ Afq,
        const float* __restrict__ Afk,
        const unsigned short* __restrict__ Btw,   // W1t; W2t contiguous +1M
        const float* __restrict__ b1,
        const float* __restrict__ b2,
        unsigned short* __restrict__ Cout) {
    const int M = 8192, N = 1024, K = 1024;
    __shared__ __align__(16) float Asf[256 * 64];          // 64 KB
    __shared__ __align__(16) unsigned short Bs[128 * 64];  // 16 KB

    // ---- XCD-aware tile remap (bijective; Rt = 32*2 = 64, %8==0) ----
    int bx, by, bz;
    {
        const int nx = gridDim.x;
        const int Rt = gridDim.y * gridDim.z;
        int flat = ((int)blockIdx.z * gridDim.y + blockIdx.y) * nx + blockIdx.x;
        int rpx = Rt >> 3;
        int c = flat & 7;
        int j = flat >> 3;
        bx = j / rpx;
        int yg = c * rpx + (j - bx * rpx);
        bz = yg / gridDim.y;
        by = yg - bz * gridDim.y;
    }

    const float* Af = bz ? Afk : Afq;
    const unsigned short* Bt = Btw + (long)bz * (1024 * 1024);

    const int t = threadIdx.x;
    const int lane = t & 63;
    const int wave = t >> 6;               // 0..7
    const int wm = wave >> 1, wn = wave & 1;  // 4M x 2N
    const int row0 = by * 256;
    const int col0 = bx * 128;

    // ---- A staging addressing (fp32, 8 issues/wave/K-step) ----
    const int srow4 = lane >> 4;           // 0..3
    const float* fsrc[8];
#pragma unroll
    for (int i = 0; i < 8; i++) {
        const int rw = wave * 32 + i * 4 + srow4;
        const int ch = (lane & 15) ^ ((i * 4 + srow4) & 15);
        fsrc[i] = Af + (long)(row0 + rw) * K + ch * 4;
    }

    // ---- B staging addressing (bf16, unchanged proven path) ----
    const int rS = lane >> 3;
    const int kOffS = ((lane & 7) ^ rS) * 8;
    const unsigned short* gB[2];
    unsigned short* lB[2];
#pragma unroll
    for (int i = 0; i < 2; i++) {
        const int rowl = wave * 16 + i * 8;
        gB[i] = Bt + (long)(col0 + rowl + rS) * K + kOffS;
        lB[i] = Bs + rowl * 64;
    }

    const int lr = lane & 15;
    const int quad = lane >> 4;
    const int pcB0 = (quad ^ (lr & 7)) * 8;
    const int pcB1 = ((4 + quad) ^ (lr & 7)) * 8;

    f32x4 acc[4][4];
#pragma unroll
    for (int i = 0; i < 4; i++)
#pragma unroll
        for (int j = 0; j < 4; j++) acc[i][j] = f32x4{0.f, 0.f, 0.f, 0.f};

    for (int k0 = 0; k0 < K; k0 += 64) {
#pragma unroll
        for (int i = 0; i < 2; i++) load16_to_lds(gB[i] + k0, lB[i]);
#pragma unroll
        for (int i = 0; i < 8; i++) {
            __builtin_amdgcn_global_load_lds(
                (gbl_void*)(fsrc[i] + k0),
                (lds_void*)(Asf + (wave * 32 + i * 4) * 64), 16, 0, 0);
        }
        __syncthreads();

#pragma unroll
        for (int ks = 0; ks < 2; ks++) {
            // A fragments: fp32 LDS -> bf16 regs
            const int c0 = ks * 8 + quad * 2;
            const int p0 = (c0 ^ lr) * 4;          // fp32 elems
            const int p1 = ((c0 + 1) ^ lr) * 4;
            bf16x8 a[4], b[4];
#pragma unroll
            for (int i = 0; i < 4; i++) {
                const float* base = Asf + (wm * 64 + i * 16 + lr) * 64;
                float4 lo = *(const float4*)(base + p0);
                float4 hi = *(const float4*)(base + p1);
                unsigned w0, w1, w2, w3;
                asm("v_cvt_pk_bf16_f32 %0, %1, %2" : "=v"(w0) : "v"(lo.x), "v"(lo.y));
                asm("v_cvt_pk_bf16_f32 %0, %1, %2" : "=v"(w1) : "v"(lo.z), "v"(lo.w));
                asm("v_cvt_pk_bf16_f32 %0, %1, %2" : "=v"(w2) : "v"(hi.x), "v"(hi.y));
                asm("v_cvt_pk_bf16_f32 %0, %1, %2" : "=v"(w3) : "v"(hi.z), "v"(hi.w));
                a[i] = __builtin_bit_cast(bf16x8, u32x4{w0, w1, w2, w3});
            }
            const int pc = ks ? pcB1 : pcB0;
#pragma unroll
            for (int j = 0; j < 4; j++)
                b[j] = __builtin_bit_cast(bf16x8,
                    *(const short8*)(Bs + (wn * 64 + j * 16 + lr) * 64 + pc));
#pragma unroll
            for (int i = 0; i < 4; i++)
#pragma unroll
                for (int j = 0; j < 4; j++)
                    acc[i][j] = __builtin_amdgcn_mfma_f32_16x16x32_bf16(
                        a[i], b[j], acc[i][j], 0, 0, 0);
        }
        __syncthreads();
    }

    // ---- epilogue: bf16 out + bias ----
    const long cbase = (long)bz * (long)M * N;
    const float* bp = bz ? b2 : b1;
#pragma unroll
    for (int j = 0; j < 4; j++) {
        const int gcol = col0 + wn * 64 + j * 16 + lr;
        const float bv = bp[gcol];
#pragma unroll
        for (int i = 0; i < 4; i++) {
            const int growb = row0 + wm * 64 + i * 16 + quad * 4;
#pragma unroll
            for (int r = 0; r < 4; r++) {
                float val = acc[i][j][r] + bv;
                Cout[cbase + (long)(growb + r) * N + gcol] = f2b(val);
            }
        }
    }
}

// ---------------------------------------------------------------------------
// 256x128 bf16 GEMM (proven engine) -- used for score (MODE 1).
// ---------------------------------------------------------------------------
template <int MODE>
__global__ __launch_bounds__(512, 4) void gemm256_kernel(
                               const unsigned short* __restrict__ A,
                               const unsigned short* __restrict__ Bt,
                               float* __restrict__ rowsum,
                               void* __restrict__ Cout,
                               int M, int N, int K,
                               float scale,
                               long sA, long sB, long sC) {
    __shared__ __align__(16) unsigned short As[256 * 64];  // 32 KB
    __shared__ __align__(16) unsigned short Bs[128 * 64];  // 16 KB

    // ---- XCD-aware tile remap (bijective) ----
    int bx, by, bz;
    {
        const int nx = gridDim.x;
        const int Rt = gridDim.y * gridDim.z;
        if ((Rt & 7) == 0) {
            int flat = ((int)blockIdx.z * gridDim.y + blockIdx.y) * nx + blockIdx.x;
            int rpx = Rt >> 3;
            int c = flat & 7;
            int j = flat >> 3;
            bx = j / rpx;
            int yg = c * rpx + (j - bx * rpx);
            bz = yg / gridDim.y;
            by = yg - bz * gridDim.y;
        } else {
            bx = blockIdx.x; by = blockIdx.y; bz = blockIdx.z;
        }
    }

    A  += (long)bz * sA;
    Bt += (long)bz * sB;

    const int t = threadIdx.x;
    const int lane = t & 63;
    const int wave = t >> 6;               // 0..7
    const int wm = wave >> 1, wn = wave & 1;  // 4M x 2N
    const int row0 = by * 256;
    const int col0 = bx * 128;

    const int rS = lane >> 3;
    const int kOffS = ((lane & 7) ^ rS) * 8;
    const unsigned short* gA[4];
    unsigned short* lA[4];
    const unsigned short* gB[2];
    unsigned short* lB[2];
#pragma unroll
    for (int i = 0; i < 4; i++) {
        const int rowl = wave * 32 + i * 8;
        gA[i] = A + (long)(row0 + rowl + rS) * K + kOffS;
        lA[i] = As + rowl * 64;
    }
#pragma unroll
    for (int i = 0; i < 2; i++) {
        const int rowl = wave * 16 + i * 8;
        gB[i] = Bt + (long)(col0 + rowl + rS) * K + kOffS;
        lB[i] = Bs + rowl * 64;
    }

    const int lr = lane & 15;
    const int quad = lane >> 4;
    const int pc0 = (quad ^ (lr & 7)) * 8;
    const int pc1 = ((4 + quad) ^ (lr & 7)) * 8;

    f32x4 acc[4][4];
#pragma unroll
    for (int i = 0; i < 4; i++)
#pragma unroll
        for (int j = 0; j < 4; j++) acc[i][j] = f32x4{0.f, 0.f, 0.f, 0.f};

    for (int k0 = 0; k0 < K; k0 += 64) {
#pragma unroll
        for (int i = 0; i < 4; i++) load16_to_lds(gA[i] + k0, lA[i]);
#pragma unroll
        for (int i = 0; i < 2; i++) load16_to_lds(gB[i] + k0, lB[i]);
        __syncthreads();

#pragma unroll
        for (int ks = 0; ks < 2; ks++) {
            const int pc = ks ? pc1 : pc0;
            bf16x8 a[4], b[4];
#pragma unroll
            for (int i = 0; i < 4; i++) {
                a[i] = __builtin_bit_cast(bf16x8,
                    *(const short8*)(As + (wm * 64 + i * 16 + lr) * 64 + pc));
                b[i] = __builtin_bit_cast(bf16x8,
                    *(const short8*)(Bs + (wn * 64 + i * 16 + lr) * 64 + pc));
            }
#pragma unroll
            for (int i = 0; i < 4; i++)
#pragma unroll
                for (int j = 0; j < 4; j++)
                    acc[i][j] = __builtin_amdgcn_mfma_f32_16x16x32_bf16(
                        a[i], b[j], acc[i][j], 0, 0, 0);
        }
        __syncthreads();
    }

    const long cbase = (long)bz * sC;

    if (MODE == 1) {
        float psum[4][4];
#pragma unroll
        for (int i = 0; i < 4; i++)
#pragma unroll
            for (int r = 0; r < 4; r++) psum[i][r] = 0.f;
#pragma unroll
        for (int j = 0; j < 4; j++) {
            const int gcol = col0 + wn * 64 + j * 16 + lr;
#pragma unroll
            for (int i = 0; i < 4; i++) {
                const int growb = row0 + wm * 64 + i * 16 + quad * 4;
#pragma unroll
                for (int r = 0; r < 4; r++) {
                    float e = __expf(acc[i][j][r] * scale);
                    psum[i][r] += e;
                    ((unsigned short*)Cout)[cbase + (long)(growb + r) * N + gcol] = f2b(e);
                }
            }
        }
        // reduce across the 16 lr lanes (xor masks 1,2,4,8 keep quad bits)
#pragma unroll
        for (int i = 0; i < 4; i++)
#pragma unroll
            for (int r = 0; r < 4; r++) {
                float s = psum[i][r];
                s += __shfl_xor(s, 1);
                s += __shfl_xor(s, 2);
                s += __shfl_xor(s, 4);
                s += __shfl_xor(s, 8);
                if (lr == 0) {
                    const int grow = row0 + wm * 64 + i * 16 + quad * 4 + r;
                    atomicAdd(rowsum + (long)bz * M + grow, s);
                }
            }
    }
}

// ---------------------------------------------------------------------------
// att: 128x128 tile @ 512 thr (8 waves 4Mx2N, per-wave 32x64, acc[2][4]).
// out = (sc @ vT^T) / rowsum[row], fp32.  512 blocks = 2/CU.
// ---------------------------------------------------------------------------
__global__ __launch_bounds__(512, 4) void att512_kernel(
        const unsigned short* __restrict__ A,   // sc [B][2048][2048] bf16
        const unsigned short* __restrict__ Bt,  // vT [B][1024][2048] bf16
        const float* __restrict__ rowsum,
        float* __restrict__ out) {
    __shared__ __align__(16) unsigned short As[128 * 64];  // 16 KB
    __shared__ __align__(16) unsigned short Bs[128 * 64];  // 16 KB

    int bx, by, bz;
    {
        const int nx = gridDim.x;
        const int Rt = gridDim.y * gridDim.z;
        int flat = ((int)blockIdx.z * gridDim.y + blockIdx.y) * nx + blockIdx.x;
        int rpx = Rt >> 3;
        int c = flat & 7;
        int j = flat >> 3;
        bx = j / rpx;
        int yg = c * rpx + (j - bx * rpx);
        bz = yg / gridDim.y;
        by = yg - bz * gridDim.y;
    }

    const int M = 2048, N = 1024, K = 2048;
    const long sA = (long)M * K, sB = (long)N * K, sC = (long)M * N;
    const unsigned short* Ab  = A  + (long)bz * sA;
    const unsigned short* Btb = Bt + (long)bz * sB;

    const int t = threadIdx.x;
    const int lane = t & 63;
    const int w = t >> 6;
    const int wm = w >> 1, wn = w & 1;     // 4M x 2N
    const int row0 = by * 128;
    const int col0 = bx * 128;

    const int rS = lane >> 3;
    const int kOffS = ((lane & 7) ^ rS) * 8;
    const unsigned short* gA[2];
    unsigned short* lA[2];
    const unsigned short* gB[2];
    unsigned short* lB[2];
#pragma unroll
    for (int i = 0; i < 2; i++) {
        const int rowl = w * 16 + i * 8;
        gA[i] = Ab  + (long)(row0 + rowl + rS) * K + kOffS;
        lA[i] = As + rowl * 64;
        gB[i] = Btb + (long)(col0 + rowl + rS) * K + kOffS;
        lB[i] = Bs + rowl * 64;
    }

    const int lr = lane & 15;
    const int quad = lane >> 4;
    const int pc0 = (quad ^ (lr & 7)) * 8;
    const int pc1 = ((4 + quad) ^ (lr & 7)) * 8;

    f32x4 acc[2][4];
#pragma unroll
    for (int i = 0; i < 2; i++)
#pragma unroll
        for (int j = 0; j < 4; j++) acc[i][j] = f32x4{0.f, 0.f, 0.f, 0.f};

    for (int k0 = 0; k0 < K; k0 += 64) {
#pragma unroll
        for (int i = 0; i < 2; i++) {
            load16_to_lds(gA[i] + k0, lA[i]);
            load16_to_lds(gB[i] + k0, lB[i]);
        }
        __syncthreads();
#pragma unroll
        for (int ks = 0; ks < 2; ks++) {
            const int pc = ks ? pc1 : pc0;
            bf16x8 a[2], b[4];
#pragma unroll
            for (int i = 0; i < 2; i++)
                a[i] = __builtin_bit_cast(bf16x8,
                    *(const short8*)(As + (wm * 32 + i * 16 + lr) * 64 + pc));
#pragma unroll
            for (int j = 0; j < 4; j++)
                b[j] = __builtin_bit_cast(bf16x8,
                    *(const short8*)(Bs + (wn * 64 + j * 16 + lr) * 64 + pc));
#pragma unroll
            for (int i = 0; i < 2; i++)
#pragma unroll
                for (int j = 0; j < 4; j++)
                    acc[i][j] = __builtin_amdgcn_mfma_f32_16x16x32_bf16(
                        a[i], b[j], acc[i][j], 0, 0, 0);
        }
        __syncthreads();
    }

    const long cbase = (long)bz * sC;
#pragma unroll
    for (int i = 0; i < 2; i++) {
        const int growb = row0 + wm * 32 + i * 16 + quad * 4;
#pragma unroll
        for (int r = 0; r < 4; r++) {
            const float inv = 1.0f / rowsum[(long)bz * M + growb + r];
#pragma unroll
            for (int j = 0; j < 4; j++) {
                const int gcol = col0 + wn * 64 + j * 16 + lr;
                out[cbase + (long)(growb + r) * N + gcol] = acc[i][j][r] * inv;
            }
        }
    }
}

// ---------------------------------------------------------------------------
extern "C" void kernel_launch(void* const* d_in, const int* in_sizes, int n_in,
                              void* d_out, int out_size, void* d_ws, size_t ws_size,
                              hipStream_t stream) {
    const float* q   = (const float*)d_in[0];
    const float* k   = (const float*)d_in[1];
    const float* v   = (const float*)d_in[2];
    const float* W1w = (const float*)d_in[3];
    const float* W1b = (const float*)d_in[4];
    const float* W2w = (const float*)d_in[5];
    const float* W2b = (const float*)d_in[6];
    float* out = (float*)d_out;

    const int B = 4, SQ = 2048, SK = 2048, D = 1024, U = 1024;
    char* ws = (char*)d_ws;
    const size_t MB = 1024 * 1024;
    unsigned short* vT  = (unsigned short*)(ws + 32 * MB);  // 16 MB [B][D][SK]
    unsigned short* W1t = (unsigned short*)(ws + 48 * MB);  // 2 MB  [U][D]
    unsigned short* W2t = (unsigned short*)(ws + 50 * MB);  // 2 MB (contiguous after W1t)
    unsigned short* l1  = (unsigned short*)(ws + 52 * MB);  // 16 MB [B*SQ][U]
    unsigned short* l2  = (unsigned short*)(ws + 68 * MB);  // 16 MB
    unsigned short* sc  = (unsigned short*)(ws + 0);        // 32 MB [B][SQ][SK]

    // rowsum: fresh slot at 84 MB, zeroed inside prep (no memset dispatch);
    // fallback: W2t slot + memset between l1l2 and score.
    float* rowsum;
    bool prep_zeroes_rowsum;
    if (ws_size >= 85 * MB) {
        rowsum = (float*)(ws + 84 * MB);
        prep_zeroes_rowsum = true;
    } else {
        rowsum = (float*)(ws + 50 * MB);
        prep_zeroes_rowsum = false;
    }

    // 1: prep (v/W transposes + rowsum zero) -- q/k casts in-GEMM (l1l2f)
    prep_kernel<<<dim3(64, 8, 6), 256, 0, stream>>>(
        v, W1w, W2w, vT, W1t, W2t,
        prep_zeroes_rowsum ? rowsum : nullptr);
    // 2: merged l1 = q@W1+b1 (bz=0), l2 = k@W2+b2 (bz=1); A staged fp32
    //    via global_load_lds, cast at fragment read (l1l2f engine)
    l1l2f_kernel<<<dim3(U / 128, (B * SQ) / 256, 2), 512, 0, stream>>>(
        q, k, W1t, W1b, W2b, l1);
    // 3 (fallback only): zero rowsum in the W2t slot after l1l2 read it
    if (!prep_zeroes_rowsum)
        hipMemsetAsync(rowsum, 0, (size_t)B * SQ * sizeof(float), stream);
    // 4: sc = exp(l1 @ l2^T / sqrt(SK)) bf16 + rowsum atomics
    const float invs = 1.0f / sqrtf((float)SK);
    gemm256_kernel<1><<<dim3(SK / 128, SQ / 256, B), 512, 0, stream>>>(
        l1, l2, rowsum, sc, SQ, SK, U, invs,
        (long)SQ * U, (long)SK * U, (long)SQ * SK);
    // 5: att = (sc @ vT^T) / rowsum[row]  (fp32 out) -- 512-thr 128^2
    att512_kernel<<<dim3(D / 128, SQ / 128, B), 512, 0, stream>>>(
        sc, vT, rowsum, out);
}